// Round 1
// baseline (49.490 us; speedup 1.0000x reference)
//
#include <hip/hip_runtime.h>
#include <hip/hip_bf16.h>

#define B_   4
#define C_   64
#define H_   128
#define W_   160
#define N_   9
#define HW_  (H_*W_)            // 20480
#define NPTS (B_*N_*H_*W_)      // 737280
#define EPS_ 1e-5f

// d_ws layout:
//   [0, TFEAT_BYTES):  bf16 transposed features [B][H][W][C]
//   [TFEAT_BYTES, +289*4): fused f32 MLP weights:
//     fw0[16*8] @0, fb0[16] @128, fw1[8*16] @144, fb1[8] @272, fsim[8] @280, bsim @288
#define TFEAT_BYTES (B_*HW_*C_*2)   // 10,485,760

__device__ __forceinline__ float bflo(unsigned u) { return __uint_as_float(u << 16); }
__device__ __forceinline__ float bfhi(unsigned u) { return __uint_as_float(u & 0xffff0000u); }

// Kernel A: [B,C,H,W] f32 -> [B,H,W,C] bf16 tiled transpose; block 0 also fuses BN into MLP weights.
__global__ __launch_bounds__(256) void transpose_fuse(
    const float* __restrict__ feat,
    const float* __restrict__ w0, const float* __restrict__ g0, const float* __restrict__ b0,
    const float* __restrict__ m0, const float* __restrict__ v0,
    const float* __restrict__ w1, const float* __restrict__ g1, const float* __restrict__ b1,
    const float* __restrict__ m1, const float* __restrict__ v1,
    const float* __restrict__ wsim, const float* __restrict__ bsim,
    __hip_bfloat16* __restrict__ tf, float* __restrict__ fw)
{
    __shared__ float tile[64][65];   // +1 pad: conflict-free transpose
    const int blk = blockIdx.x;      // 0..1279
    const int bi  = blk / 320;
    const int hw0 = (blk - bi * 320) * 64;
    const int t   = threadIdx.x;
    const int lhw = t & 63;
    const int cq  = t >> 6;          // 0..3

    const float* fb = feat + (size_t)bi * C_ * HW_;
    #pragma unroll
    for (int k = 0; k < 16; ++k) {
        int c = cq * 16 + k;
        tile[c][lhw] = fb[c * HW_ + hw0 + lhw];   // coalesced along hw
    }
    __syncthreads();
    const int c_out = t & 63;
    #pragma unroll
    for (int k = 0; k < 16; ++k) {
        int hw = cq * 16 + k;
        tf[((size_t)bi * HW_ + hw0 + hw) * C_ + c_out] =
            __float2bfloat16(tile[c_out][hw]);    // coalesced along c
    }

    if (blk == 0) {
        if (t < 16) {                       // layer0 rows
            float inv = g0[t] * rsqrtf(v0[t] + EPS_);
            for (int g = 0; g < 8; ++g) fw[t * 8 + g] = w0[t * 8 + g] * inv;
            fw[128 + t] = b0[t] - m0[t] * inv;
        } else if (t < 24) {                // layer1 rows
            int o = t - 16;
            float inv = g1[o] * rsqrtf(v1[o] + EPS_);
            for (int c = 0; c < 16; ++c) fw[144 + o * 16 + c] = w1[o * 16 + c] * inv;
            fw[272 + o] = b1[o] - m1[o] * inv;
        } else if (t == 24) {               // sim layer (no BN)
            for (int c = 0; c < 8; ++c) fw[280 + c] = wsim[c];
            fw[288] = bsim[0];
        }
    }
}

// Kernel B: 8 lanes per output point; lane j owns channel-group j (8 bf16 = one uint4).
__global__ __launch_bounds__(256) void fwnet_main(
    const float* __restrict__ grid, const __hip_bfloat16* __restrict__ tf,
    const float* __restrict__ fw, float* __restrict__ out)
{
    __shared__ float sw[289];
    __shared__ float lds_w[32][8];
    __shared__ float lds_x0[32][16];

    const int t = threadIdx.x;
    for (int i = t; i < 289; i += 256) sw[i] = fw[i];
    __syncthreads();

    const int pt = t >> 3;                       // point slot in block (0..31)
    const int j  = t & 7;                        // channel group / lane-in-point
    const int p  = blockIdx.x * 32 + pt;         // global point id (< 737280, exact grid)

    // decode p -> (bi, h, px);  grid row index == p / W_ by construction
    const int px  = p % W_;
    const int row = p / W_;
    const int bn  = row / H_;
    const int h   = row - bn * H_;
    const int bi  = bn / N_;

    const float2 gv = ((const float2*)grid)[p];
    float ix = fminf(fmaxf(((gv.x + 1.0f) * (float)W_ - 1.0f) * 0.5f, 0.0f), (float)(W_ - 1));
    float iy = fminf(fmaxf(((gv.y + 1.0f) * (float)H_ - 1.0f) * 0.5f, 0.0f), (float)(H_ - 1));
    float x0f = floorf(ix), y0f = floorf(iy);
    float wx = ix - x0f, wy = iy - y0f;
    int x0 = (int)x0f, y0 = (int)y0f;
    int x1 = min(x0 + 1, W_ - 1), y1 = min(y0 + 1, H_ - 1);
    float w00 = (1.0f - wx) * (1.0f - wy);
    float w01 = wx * (1.0f - wy);
    float w10 = (1.0f - wx) * wy;
    float w11 = wx * wy;

    const __hip_bfloat16* Tb = tf + (size_t)bi * HW_ * C_;
    const uint4* p00 = (const uint4*)(Tb + (y0 * W_ + x0) * C_) + j;
    const uint4* p01 = (const uint4*)(Tb + (y0 * W_ + x1) * C_) + j;
    const uint4* p10 = (const uint4*)(Tb + (y1 * W_ + x0) * C_) + j;
    const uint4* p11 = (const uint4*)(Tb + (y1 * W_ + x1) * C_) + j;
    const uint4* prf = (const uint4*)(Tb + (h  * W_ + px) * C_) + j;

    const uint4 a  = *p00;
    const uint4 b2 = *p01;
    const uint4 c2 = *p10;
    const uint4 d2 = *p11;
    const uint4 rr = *prf;

    float acc = 0.0f;
    {
        auto acc2 = [&](unsigned ua, unsigned ub, unsigned uc, unsigned ud, unsigned ur) {
            float s0 = w00 * bflo(ua) + w01 * bflo(ub) + w10 * bflo(uc) + w11 * bflo(ud);
            float s1 = w00 * bfhi(ua) + w01 * bfhi(ub) + w10 * bfhi(uc) + w11 * bfhi(ud);
            acc += s0 * bflo(ur) + s1 * bfhi(ur);
        };
        acc2(a.x, b2.x, c2.x, d2.x, rr.x);
        acc2(a.y, b2.y, c2.y, d2.y, rr.y);
        acc2(a.z, b2.z, c2.z, d2.z, rr.z);
        acc2(a.w, b2.w, c2.w, d2.w, rr.w);
    }

    lds_w[pt][j] = acc * 0.125f;    // mean over the 8 channels of the group
    __syncthreads();

    // layer 0: lane j computes outputs j and j+8
    float wv[8];
    #pragma unroll
    for (int g = 0; g < 8; ++g) wv[g] = lds_w[pt][g];
    float o0 = sw[128 + j];
    float o1 = sw[128 + j + 8];
    #pragma unroll
    for (int g = 0; g < 8; ++g) {
        o0 += sw[j * 8 + g] * wv[g];
        o1 += sw[(j + 8) * 8 + g] * wv[g];
    }
    o0 = fmaxf(o0, 0.0f);
    o1 = fmaxf(o1, 0.0f);
    lds_x0[pt][j]     = o0;
    lds_x0[pt][j + 8] = o1;
    __syncthreads();

    // layer 1: lane j computes output j
    float x1v = sw[272 + j];
    #pragma unroll
    for (int cc = 0; cc < 16; ++cc) x1v += sw[144 + j * 16 + cc] * lds_x0[pt][cc];
    x1v = fmaxf(x1v, 0.0f);

    // sim layer: dot over 8 lanes
    float part = sw[280 + j] * x1v;
    part += __shfl_xor(part, 1);
    part += __shfl_xor(part, 2);
    part += __shfl_xor(part, 4);

    if (j == 0) {
        float s = part + sw[288];
        out[p] = 1.0f / (1.0f + expf(-s));
    }
}

extern "C" void kernel_launch(void* const* d_in, const int* in_sizes, int n_in,
                              void* d_out, int out_size, void* d_ws, size_t ws_size,
                              hipStream_t stream) {
    const float* feat = (const float*)d_in[0];
    const float* grid = (const float*)d_in[1];
    const float* w0   = (const float*)d_in[2];
    const float* g0   = (const float*)d_in[3];
    const float* b0   = (const float*)d_in[4];
    const float* m0   = (const float*)d_in[5];
    const float* v0   = (const float*)d_in[6];
    const float* w1   = (const float*)d_in[7];
    const float* g1   = (const float*)d_in[8];
    const float* b1   = (const float*)d_in[9];
    const float* m1   = (const float*)d_in[10];
    const float* v1   = (const float*)d_in[11];
    const float* wsim = (const float*)d_in[12];
    const float* bsim = (const float*)d_in[13];

    __hip_bfloat16* tf = (__hip_bfloat16*)d_ws;
    float* fw = (float*)((char*)d_ws + TFEAT_BYTES);

    hipLaunchKernelGGL(transpose_fuse, dim3(B_ * (HW_ / 64)), dim3(256), 0, stream,
                       feat, w0, g0, b0, m0, v0, w1, g1, b1, m1, v1, wsim, bsim, tf, fw);

    hipLaunchKernelGGL(fwnet_main, dim3(NPTS / 32), dim3(256), 0, stream,
                       grid, tf, fw, (float*)d_out);
}